// Round 10
// baseline (6016.536 us; speedup 1.0000x reference)
//
#include <hip/hip_runtime.h>
#include <math.h>
#include <stdint.h>

// ---------------------------------------------------------------------------
// Speller decoder, persistent kernel, 256 blocks x 512 threads (1 block/CU).
// R13: halve the coherent broadcast. R12's counters closed the budget:
// dur/step == (FETCH+WRITE)/step / 830 GB/s -- the kernel runs AT the
// L2-bypass path's effective throughput ceiling; every coherent byte is
// wall time. The broadcast volume scales with READER BLOCK COUNT, so:
// 256x512t blocks (was 512x256t). Gate role = 128 blocks x 4 units
// (Wg[16],Wpg[4] in LDS, ~123 KB); logits role = 125 blocks x 40 vocab
// rows (Wc[40]); attention = all 256 blocks x 2 chunks (per-wave code
// identical: wave = (head, 64-t chunk), tc=(blk&7)*2+sub). x-broadcast
// readers halve (W1 16->8, W3 32->16, W4 16->8 MB/step); h/HID stores are
// now 16B-contiguous (4 units) cutting the 64B-line write amplification;
// out rows 40 floats contiguous; gsync population halves.
// R12: MLP fused into gate blocks' A-part. R8: A-part (ctx|h) pipelined
// into W3. R7/R6: LF register-resident. R5: parallel per-batch W4 merge.
// R3: monotonic counter barriers, relaxed AGENT-scope atomics via L3.
// ---------------------------------------------------------------------------

#define NB 256
#define NT 512

constexpr int Tv = 1024, Vv = 5000, STEPS = 64;

// ---- u32 counter region (all monotonic, zeroed by init kernel) ----
constexpr int MCNT = 0;               // master barrier counter
constexpr int GEN  = 16;              // barrier generation
constexpr int GCNT = 64;              // 16 group counters, stride 16
constexpr int GFLG = 1024;            // 16 group release flags, stride 32
constexpr int ACNT = 2048;            // 32 attn-merge counters, stride 16
constexpr int LCNT = 2560;            // single logits-arrival counter
constexpr int WSU  = 4096;

// ---- float region offsets (wsf = (float*)ws + WSU) ----
constexpr int XH   = 0;                    // [32][1024] = emb(512) | ctx(512)
constexpr int HB   = XH + 32*1024;         // [2][32][512] h double-buffer
constexpr int HID  = HB + 2*32*512;        // [32][512]
constexpr int PART = HID + 32*512;         // [32][4][16][130] attn partials
constexpr int E3   = PART + 32*4*16*130;   // [32][1024] head-3 energies
constexpr int PM   = E3 + 32*1024;         // [32][256] chunk max
constexpr int PSUM = PM + 32*256;          // [32][256] chunk sumexp
constexpr int PIDX = PSUM + 32*256;        // [32][256] chunk argmax (int)
constexpr int MLS  = PIDX + 32*256;        // [32][2] (max, lse)

__device__ __forceinline__ float sigm(float x) { return 1.f / (1.f + expf(-x)); }

// ---- coherent (L3, sc0 sc1) access helpers: relaxed agent atomics ----
__device__ __forceinline__ float ld4(const float* p) {
  return __hip_atomic_load(const_cast<float*>(p), __ATOMIC_RELAXED, __HIP_MEMORY_SCOPE_AGENT);
}
__device__ __forceinline__ float2 ld8(const float* p) {
  unsigned long long u = __hip_atomic_load(
      reinterpret_cast<unsigned long long*>(const_cast<float*>(p)),
      __ATOMIC_RELAXED, __HIP_MEMORY_SCOPE_AGENT);
  union { unsigned long long u; float2 f; } c; c.u = u; return c.f;
}
__device__ __forceinline__ int ld4i(const int* p) {
  return (int)__hip_atomic_load(reinterpret_cast<unsigned*>(const_cast<int*>(p)),
                                __ATOMIC_RELAXED, __HIP_MEMORY_SCOPE_AGENT);
}
__device__ __forceinline__ void st4(float* p, float v) {
  __hip_atomic_store(p, v, __ATOMIC_RELAXED, __HIP_MEMORY_SCOPE_AGENT);
}
__device__ __forceinline__ void st8(float* p, float2 v) {
  union { float2 f; unsigned long long u; } c; c.f = v;
  __hip_atomic_store(reinterpret_cast<unsigned long long*>(p), c.u,
                     __ATOMIC_RELAXED, __HIP_MEMORY_SCOPE_AGENT);
}
__device__ __forceinline__ void st4i(int* p, int v) {
  __hip_atomic_store(reinterpret_cast<unsigned*>(p), (unsigned)v,
                     __ATOMIC_RELAXED, __HIP_MEMORY_SCOPE_AGENT);
}
__device__ __forceinline__ unsigned ld_rlx(unsigned* p) {
  return __hip_atomic_load(p, __ATOMIC_RELAXED, __HIP_MEMORY_SCOPE_AGENT);
}
__device__ __forceinline__ void st_rlx(unsigned* p, unsigned v) {
  __hip_atomic_store(p, v, __ATOMIC_RELAXED, __HIP_MEMORY_SCOPE_AGENT);
}
__device__ __forceinline__ unsigned add_rlx(unsigned* p, unsigned v) {
  return __hip_atomic_fetch_add(p, v, __ATOMIC_RELAXED, __HIP_MEMORY_SCOPE_AGENT);
}

// Device barrier: 16 groups x 16 blocks. __syncthreads drains vmcnt (sc1
// stores then in L3 = globally visible); counters are relaxed sc1 atomics.
__device__ __forceinline__ void gsync(unsigned* wsu, int blk, int tid, unsigned& myGen) {
  __syncthreads();
  if (tid == 0) {
    const unsigned target = ++myGen;
    const int grp = blk >> 4;
    unsigned o = add_rlx(&wsu[GCNT + grp*16], 1u);
    if (o == target*16u - 1u) {
      unsigned o2 = add_rlx(&wsu[MCNT], 1u);
      if (o2 == target*16u - 1u) st_rlx(&wsu[GEN], target);
    }
    if ((blk & 15) == 0) {
      while (ld_rlx(&wsu[GEN]) != target) __builtin_amdgcn_s_sleep(8);
      st_rlx(&wsu[GFLG + grp*32], target);
    } else {
      while (ld_rlx(&wsu[GFLG + grp*32]) != target) __builtin_amdgcn_s_sleep(8);
    }
  }
  __syncthreads();
}

__global__ void speller_init(const float* __restrict__ LF, const float* __restrict__ Emb,
                             float* __restrict__ wsf, unsigned* __restrict__ wsu) {
  int b = blockIdx.x;
  for (int i = threadIdx.x; i < 512; i += 256) {
    st4(wsf + XH + b*1024 + i,       Emb[i]);                    // emb row 0
    st4(wsf + XH + b*1024 + 512 + i, LF[(size_t)b*Tv*512 + i]);  // ctx0 = LF[b,0,:]
    st4(wsf + HB + b*512 + i,        0.f);                       // h0 (buffer 0)
  }
  if (b == 0) for (int i = threadIdx.x; i < WSU; i += 256) st_rlx(wsu + i, 0u);
}

// Gate blocks (blk<128): Wg = 16 gate rows (4 gates x 4 units, r=g*4+uu);
// Wpg = 4 Wp rows in GATE-space K layout (ctx@[512,1024), h@[1024,1536)).
struct LdsA { float Wg[16][1536]; float Wpg[4][1536]; float gb[16]; float bpg[4]; };
struct LdsB { float Wc[40][512]; float bcl[40]; };
union  LdsU { LdsA a; LdsB b; };

// Fused A-part of next step's gates + this step's 4 MLP rows, one batch b
// per thread-slot, 16 k-lanes. K in [512,1536) = ctx | h.
__device__ __forceinline__ void gate_accum_A(float acc[16], float accW[4],
                                             const float* __restrict__ wsf,
                                             const float (&Wg)[16][1536],
                                             const float (&Wpg)[4][1536],
                                             int ks, int b, int hbuf) {
#pragma unroll 2
  for (int q = 0; q < 8; ++q) {              // ctx: k in [512,1024)
    const int k4 = 512 + (q*16 + ks)*4;
    const float* p = wsf + XH + (size_t)b*1024 + k4;
    float2 xa = ld8(p), xb = ld8(p + 2);
#pragma unroll
    for (int r = 0; r < 16; ++r) {
      float4 wv = *(const float4*)(&Wg[r][k4]);
      acc[r] += wv.x*xa.x + wv.y*xa.y + wv.z*xb.x + wv.w*xb.y;
    }
#pragma unroll
    for (int r = 0; r < 4; ++r) {
      float4 wv = *(const float4*)(&Wpg[r][k4]);
      accW[r] += wv.x*xa.x + wv.y*xa.y + wv.z*xb.x + wv.w*xb.y;
    }
  }
#pragma unroll 2
  for (int q = 0; q < 8; ++q) {              // h: k in [1024,1536)
    const int k4 = (q*16 + ks)*4;
    const float* p = wsf + HB + hbuf*16384 + (size_t)b*512 + k4;
    float2 xa = ld8(p), xb = ld8(p + 2);
#pragma unroll
    for (int r = 0; r < 16; ++r) {
      float4 wv = *(const float4*)(&Wg[r][1024 + k4]);
      acc[r] += wv.x*xa.x + wv.y*xa.y + wv.z*xb.x + wv.w*xb.y;
    }
#pragma unroll
    for (int r = 0; r < 4; ++r) {
      float4 wv = *(const float4*)(&Wpg[r][1024 + k4]);
      accW[r] += wv.x*xa.x + wv.y*xa.y + wv.z*xb.x + wv.w*xb.y;
    }
  }
}

__launch_bounds__(NT, 1)
__global__ void speller_main(const float* __restrict__ LF, const float* __restrict__ Emb,
                             const float* __restrict__ Wih, const float* __restrict__ Whh,
                             const float* __restrict__ bih, const float* __restrict__ bhh,
                             const float* __restrict__ Wp,  const float* __restrict__ bp,
                             const float* __restrict__ Wc,  const float* __restrict__ bc,
                             float* __restrict__ out, unsigned* __restrict__ wsu,
                             float* __restrict__ wsf) {
  const int blk = blockIdx.x, tid = threadIdx.x;
  unsigned myGen = 0;
  __shared__ LdsU lds;
  __shared__ float scr[784];
  __shared__ int  sint[300];

  // attention identity: block = (batch ab, 2 chunks); wave = (head, chunk)
  const int ab  = blk >> 3;
  const int wavid = tid >> 6, aln = tid & 63;
  const int aw  = wavid & 3, sub = wavid >> 2;
  const int atc = (blk & 7)*2 + sub;               // chunk in [0,16)

  // ---- persistent LF slice: LF[ab, atc*64+aln, aw*128 .. +127] ----
  float4 lfr[32];
  {
    const float4* src = (const float4*)(LF +
        (((size_t)ab*Tv + atc*64 + aln)*512 + aw*128));
#pragma unroll
    for (int q = 0; q < 32; ++q) lfr[q] = src[q];
  }

  // ---------------- one-time LDS weight preload (plain cached loads) -------
  if (blk < 128) {
    const int u0 = blk * 4;
    for (int idx = tid; idx < 16*1536; idx += NT) {
      int r = idx / 1536, k = idx - r*1536;
      int g = r >> 2, uu = r & 3;
      int row = g*512 + u0 + uu;
      lds.a.Wg[r][k] = (k < 1024) ? Wih[(size_t)row*1024 + k]
                                  : Whh[(size_t)row*512 + (k-1024)];
    }
    for (int idx = tid; idx < 4*1536; idx += NT) {
      int r = idx / 1536, k = idx - r*1536;
      float v = 0.f;
      if (k >= 512) v = (k < 1024) ? Wp[(size_t)(u0+r)*1024 + k]
                                   : Wp[(size_t)(u0+r)*1024 + (k-1024)];
      lds.a.Wpg[r][k] = v;
    }
    if (tid < 16) {
      int g = tid >> 2, uu = tid & 3, row = g*512 + u0 + uu;
      lds.a.gb[tid] = bih[row] + bhh[row];
    }
    if (tid < 4) lds.a.bpg[tid] = bp[u0 + tid];
  } else {
    const int blk2 = blk - 128, v0 = blk2*40;
    if (blk2 < 125) {
      for (int idx = tid; idx < 40*512; idx += NT) {
        int vi = idx >> 9, k = idx & 511;
        lds.b.Wc[vi][k] = Wc[(size_t)(v0+vi)*512 + k];
      }
      if (tid < 40) lds.b.bcl[tid] = bc[v0+tid];
    }
  }
  __syncthreads();

  float acc[16];                     // carried partial gates (A-part pipeline)
  float accW[4];                     // this-step MLP partials (W3-local)
  float c_reg[4];                    // cell state, lives in registers all run
#pragma unroll
  for (int uu = 0; uu < 4; ++uu) c_reg[uu] = 0.f;
  float lgv[40];                     // logits carried phase4 -> next phase1

  // ---- prologue: A-part (ctx0|h0) of step 0's gates (accW discarded) ----
  if (blk < 128) {
    const int ks = tid & 15, b = tid >> 4;
#pragma unroll
    for (int r = 0; r < 16; ++r) acc[r] = 0.f;
#pragma unroll
    for (int r = 0; r < 4; ++r) accW[r] = 0.f;
    gate_accum_A(acc, accW, wsf, lds.a.Wg, lds.a.Wpg, ks, b, 0);
  }

#pragma unroll 1
  for (int s = 0; s < STEPS; ++s) {
    const int wbuf = (s + 1) & 1;

    // ===== W1: emb-part + LSTM finish (blk<128) | out-write (>=128) ========
    if (blk < 128) {
      const int u0 = blk * 4;
      const int ks = tid & 15, b = tid >> 4;
#pragma unroll 2
      for (int q = 0; q < 8; ++q) {          // emb: k in [0,512)
        const int k4 = (q*16 + ks)*4;
        const float* p = wsf + XH + (size_t)b*1024 + k4;
        float2 xa = ld8(p), xb = ld8(p + 2);
#pragma unroll
        for (int r = 0; r < 16; ++r) {
          float4 wv = *(const float4*)(&lds.a.Wg[r][k4]);
          acc[r] += wv.x*xa.x + wv.y*xa.y + wv.z*xb.x + wv.w*xb.y;
        }
      }
#pragma unroll
      for (int r = 0; r < 16; ++r) {
        float v = acc[r];
        v += __shfl_xor(v, 8); v += __shfl_xor(v, 4);
        v += __shfl_xor(v, 2); v += __shfl_xor(v, 1);
        acc[r] = v + lds.a.gb[r];
      }
      // fused LSTM pointwise (r = g*4+uu: i=uu, f=4+uu, g=8+uu, o=12+uu)
      float hnew[4];
#pragma unroll
      for (int uu = 0; uu < 4; ++uu) {
        float cn = sigm(acc[4+uu]) * c_reg[uu]
                 + sigm(acc[uu]) * tanhf(acc[8+uu]);
        c_reg[uu] = cn;
        hnew[uu] = sigm(acc[12+uu]) * tanhf(cn);
      }
      if (ks == 0) {
        st8(wsf + HB + wbuf*16384 + (size_t)b*512 + u0,
            make_float2(hnew[0], hnew[1]));
        st8(wsf + HB + wbuf*16384 + (size_t)b*512 + u0 + 2,
            make_float2(hnew[2], hnew[3]));
      }
    } else if (s > 0) {
      const int blk2 = blk - 128;
      if (blk2 < 125) {
        const int v0 = blk2 * 40, bb = tid >> 4, ks = tid & 15;
        if (ks == 0) {
          float2 ml = ld8(wsf + MLS + 2*bb);
          float sub2 = ml.x + ml.y;
#pragma unroll
          for (int vi = 0; vi < 40; ++vi)
            out[(size_t)(s-1)*160000 + (size_t)bb*5000 + v0 + vi] = lgv[vi] - sub2;
        }
      }
    }
    gsync(wsu, blk, tid, myGen);

    // ============ W2: attention from register-resident LF ===================
    {
      float* hs = scr;  // [512] decoder state
      if (tid < 256) {
        float2 hv = ld8(wsf + HB + wbuf*16384 + (size_t)ab*512 + tid*2);
        hs[tid*2] = hv.x; hs[tid*2+1] = hv.y;
      }
      __syncthreads();
      float e = 0.f;
      {
        const float4* hp = (const float4*)(hs + aw*128);
#pragma unroll
        for (int q = 0; q < 32; ++q) {
          float4 f = lfr[q], hh = hp[q];
          e += f.x*hh.x + f.y*hh.y + f.z*hh.z + f.w*hh.w;
        }
      }
      float m = e;
#pragma unroll
      for (int off = 32; off; off >>= 1) m = fmaxf(m, __shfl_xor(m, off));
      float p = expf(e - m);
      float l = p;
#pragma unroll
      for (int off = 32; off; off >>= 1) l += __shfl_xor(l, off);
      if (aw == 3) st4(wsf + E3 + (size_t)ab*1024 + atc*64 + aln, e);
      float* pr = wsf + PART + (size_t)((ab*4 + aw)*16 + atc)*130;
#pragma unroll
      for (int ch = 0; ch < 2; ++ch) {             // fully unrolled: lfr idx static
        float c[64];
#pragma unroll
        for (int q = 0; q < 16; ++q) {
          float4 f = lfr[ch*16 + q];
          c[4*q+0] = p*f.x; c[4*q+1] = p*f.y; c[4*q+2] = p*f.z; c[4*q+3] = p*f.w;
        }
#pragma unroll
        for (int o = 32; o >= 1; o >>= 1) {
#pragma unroll
          for (int j = 0; j < 32; ++j) {
            if (j < o) {
              float keep = (aln & o) ? c[j + o] : c[j];
              float send = (aln & o) ? c[j] : c[j + o];
              c[j] = keep + __shfl_xor(send, o);
            }
          }
        }
        st4(pr + 2 + ch*64 + aln, c[0]);
      }
      if (aln == 0) st8(pr, make_float2(m, l));
      __syncthreads();   // drains vmcnt: all this block's partials are in L3
      if (tid == 0) {
        unsigned old = add_rlx(&wsu[ACNT + ab*16], 1u);
        sint[0] = (old == (unsigned)(s*8 + 7));
      }
      __syncthreads();
      if (sint[0]) {                       // last arriver merges the 16 chunks
        if (tid < 256) {
          const int w2 = tid >> 6, ln2 = tid & 63;
          const float* pb = wsf + PART + (size_t)(ab*4 + w2)*16*130;
          float M = -1e30f;
          float mv[16], lv[16];
#pragma unroll
          for (int i = 0; i < 16; ++i) { float2 t = ld8(pb + i*130); mv[i] = t.x; lv[i] = t.y; M = fmaxf(M, t.x); }
          float L = 0.f;
          float sc[16];
#pragma unroll
          for (int i = 0; i < 16; ++i) { sc[i] = expf(mv[i] - M); L += lv[i] * sc[i]; }
          float cc0 = 0.f, cc1 = 0.f;
#pragma unroll
          for (int i = 0; i < 16; ++i) {
            float2 cx = ld8(pb + i*130 + 2 + 2*ln2);
            cc0 += sc[i]*cx.x; cc1 += sc[i]*cx.y;
          }
          float invL = 1.f / L;
          st8(wsf + XH + (size_t)ab*1024 + 512 + w2*128 + 2*ln2,
              make_float2(cc0*invL, cc1*invL));
          if (ln2 == 0) { scr[768 + w2*2] = M; scr[769 + w2*2] = L; }
        }
        __syncthreads();
        float M3 = scr[768 + 6], iL3 = 1.f / scr[768 + 7];
        for (int i = tid; i < 1024; i += NT)
          out[(size_t)10240000 + ((size_t)(s*32 + ab))*1024 + i] =
              expf(ld4(wsf + E3 + (size_t)ab*1024 + i) - M3) * iL3;
      }
    }
    gsync(wsu, blk, tid, myGen);

    // ===== W3: gate blocks: fused next-step A-part gates + THIS step's MLP ==
    if (blk < 128) {
      const int u0 = blk * 4;
      const int ks = tid & 15, b = tid >> 4;
#pragma unroll
      for (int r = 0; r < 16; ++r) acc[r] = 0.f;
#pragma unroll
      for (int r = 0; r < 4; ++r) accW[r] = 0.f;
      gate_accum_A(acc, accW, wsf, lds.a.Wg, lds.a.Wpg, ks, b, wbuf);
      // reduce MLP partials over the 16 k-lanes; ReLU; write HID[b][u0..u0+3]
#pragma unroll
      for (int r = 0; r < 4; ++r) {
        float v = accW[r];
        v += __shfl_xor(v, 8); v += __shfl_xor(v, 4);
        v += __shfl_xor(v, 2); v += __shfl_xor(v, 1);
        accW[r] = v + lds.a.bpg[r];
      }
      if (ks == 0) {
        st8(wsf + HID + (size_t)b*512 + u0,
            make_float2(fmaxf(accW[0], 0.f), fmaxf(accW[1], 0.f)));
        st8(wsf + HID + (size_t)b*512 + u0 + 2,
            make_float2(fmaxf(accW[2], 0.f), fmaxf(accW[3], 0.f)));
      }
    }
    gsync(wsu, blk, tid, myGen);

    // ============ W4: logits + softmax/argmax partials; parallel merge ======
    if (blk >= 128) {
      const int blk2 = blk - 128;
      if (blk2 < 125) {
        const int v0 = blk2 * 40;
        const int bb = tid >> 4, ks = tid & 15;
        const float* hb = wsf + HID + (size_t)bb*512;
        float4 xr[8];
#pragma unroll
        for (int q = 0; q < 8; ++q) {
          const float* p = hb + (q*16 + ks)*4;
          float2 a = ld8(p), b2v = ld8(p + 2);
          xr[q] = make_float4(a.x, a.y, b2v.x, b2v.y);
        }
#pragma unroll
        for (int vi = 0; vi < 40; ++vi) {
          float a = 0.f;
#pragma unroll
          for (int q = 0; q < 8; ++q) {
            float4 wv = *(const float4*)(&lds.b.Wc[vi][(q*16 + ks)*4]);
            a += wv.x*xr[q].x + wv.y*xr[q].y + wv.z*xr[q].z + wv.w*xr[q].w;
          }
          a += __shfl_xor(a, 1); a += __shfl_xor(a, 2);
          a += __shfl_xor(a, 4); a += __shfl_xor(a, 8);
          lgv[vi] = a + lds.b.bcl[vi];
        }
        float mych = lgv[0]; int ami = 0;
#pragma unroll
        for (int vi = 1; vi < 40; ++vi)
          if (lgv[vi] > mych) { mych = lgv[vi]; ami = vi; }
        float sume = 0.f;
#pragma unroll
        for (int vi = 0; vi < 40; ++vi) sume += expf(lgv[vi] - mych);
        if (ks == 0) {
          st4(wsf + PM + bb*256 + blk2, mych);
          st4(wsf + PSUM + bb*256 + blk2, sume);
          st4i((int*)(wsf + PIDX) + bb*256 + blk2, v0 + ami);
        }
      }
      __syncthreads();   // drain: this block's partials are in L3
      if (tid == 0 && blk2 < 125) add_rlx(&wsu[LCNT], 1u);
      // ---- parallel merge: block 128+b2 owns batch b2 (32 concurrent) ----
      if (blk2 < 32) {
        const int b2 = blk2;
        if (tid == 0) {
          while (ld_rlx(&wsu[LCNT]) < (unsigned)((s + 1) * 125))
            __builtin_amdgcn_s_sleep(8);
        }
        __syncthreads();               // all 125 partials visible
        float mv = -1e30f, sv = 0.f; int iv = 0x7fffffff;
        if (tid < 125) {
          mv = ld4(wsf + PM + b2*256 + tid);
          sv = ld4(wsf + PSUM + b2*256 + tid);
          iv = ld4i((const int*)(wsf + PIDX) + b2*256 + tid);
        }
        if (tid < 256) { scr[tid] = mv; sint[40 + tid] = iv; }
        __syncthreads();
        for (int off = 128; off; off >>= 1) {
          if (tid < off) {
            float m2 = scr[tid + off]; int i2 = sint[40 + tid + off];
            if (m2 > scr[tid] || (m2 == scr[tid] && i2 < sint[40 + tid])) {
              scr[tid] = m2; sint[40 + tid] = i2;
            }
          }
          __syncthreads();
        }
        float M = scr[0]; int tok = sint[40];
        __syncthreads();
        if (tid < 256) scr[tid] = sv * expf(mv - M);
        __syncthreads();
        for (int off = 128; off; off >>= 1) {
          if (tid < off) scr[tid] += scr[tid + off];
          __syncthreads();
        }
        if (tid == 0) st8(wsf + MLS + 2*b2, make_float2(M, logf(scr[0])));
        for (int i = tid; i < 256; i += NT) {
          const float2* er = (const float2*)(Emb + (size_t)tok*512);
          st8(wsf + XH + (size_t)b2*1024 + 2*i, er[i]);
        }
      }
    }
    gsync(wsu, blk, tid, myGen);
  }

  // ---------------- epilogue: step 63's log-softmax from registers ----------
  if (blk >= 128) {
    const int blk2 = blk - 128;
    if (blk2 < 125) {
      const int v0 = blk2 * 40, bb = tid >> 4, ks = tid & 15;
      if (ks == 0) {
        float2 ml = ld8(wsf + MLS + 2*bb);
        float sub2 = ml.x + ml.y;
#pragma unroll
        for (int vi = 0; vi < 40; ++vi)
          out[(size_t)63*160000 + (size_t)bb*5000 + v0 + vi] = lgv[vi] - sub2;
      }
    }
  }
}

extern "C" void kernel_launch(void* const* d_in, const int* in_sizes, int n_in,
                              void* d_out, int out_size, void* d_ws, size_t ws_size,
                              hipStream_t stream) {
  (void)in_sizes; (void)n_in; (void)out_size; (void)ws_size;
  const float* LF  = (const float*)d_in[0];
  const float* Emb = (const float*)d_in[1];
  const float* Wih = (const float*)d_in[2];
  const float* Whh = (const float*)d_in[3];
  const float* bih = (const float*)d_in[4];
  const float* bhh = (const float*)d_in[5];
  const float* Wp  = (const float*)d_in[6];
  const float* bp  = (const float*)d_in[7];
  const float* Wc  = (const float*)d_in[8];
  const float* bc  = (const float*)d_in[9];
  float* out = (float*)d_out;
  unsigned* wsu = (unsigned*)d_ws;
  float* wsf = (float*)d_ws + WSU;

  speller_init<<<32, 256, 0, stream>>>(LF, Emb, wsf, wsu);
  speller_main<<<NB, NT, 0, stream>>>(LF, Emb, Wih, Whh, bih, bhh, Wp, bp, Wc, bc,
                                      out, wsu, wsf);
}